// Round 1
// baseline (1200.122 us; speedup 1.0000x reference)
//
#include <hip/hip_runtime.h>
#include <hip/hip_bf16.h>

// B=2048 batch rows, T=2048 steps, H=32 hidden. LSTM recurrence is serial in T,
// independent per batch row. Thread = (b, k): owns h[b][k], c[b][k] and the 4
// gate rows (i,f,g,o) of W_hh for hidden index k (128 fp32 regs). All cross-
// thread traffic (h broadcast, x broadcast) is within a 32-lane group via
// __shfl — no LDS, no barriers in the 2048-step loop.

#define Bsz 2048
#define Tsz 2048
#define Hsz 32

__device__ __forceinline__ float fast_rcp(float x) {
    return __builtin_amdgcn_rcpf(x);
}
__device__ __forceinline__ float fast_sigmoid(float x) {
    // 1 / (1 + exp(-x)) via v_exp_f32 (2^x) + v_rcp_f32
    float e = __builtin_amdgcn_exp2f(-1.44269504f * x);
    return fast_rcp(1.0f + e);
}
__device__ __forceinline__ float fast_tanh(float x) {
    // tanh(x) = 2/(1+exp(-2x)) - 1 ; saturates correctly at +/-inf
    float e = __builtin_amdgcn_exp2f(-2.88539008f * x);
    return __fmaf_rn(2.0f, fast_rcp(1.0f + e), -1.0f);
}

__global__ __launch_bounds__(256, 1) void lstm_fwd_kernel(
    const float* __restrict__ x,      // (B, T)
    const float* __restrict__ w_ih,   // (4H, 1)
    const float* __restrict__ w_hh,   // (4H, H)
    const float* __restrict__ b_ih,   // (4H,)
    const float* __restrict__ b_hh,   // (4H,)
    float* __restrict__ out)          // (B, T*H)
{
    const int k  = threadIdx.x & 31;   // hidden index
    const int lb = threadIdx.x >> 5;   // local batch row (0..7)
    const int b  = blockIdx.x * 8 + lb;

    // Per-thread weights: rows k, 32+k, 64+k, 96+k of W_hh (i,f,g,o)
    float Wr[4][32];
    float wi[4], bias[4];
#pragma unroll
    for (int g = 0; g < 4; ++g) {
        const int j = g * 32 + k;
        wi[g]   = w_ih[j];
        bias[g] = b_ih[j] + b_hh[j];
#pragma unroll
        for (int kk = 0; kk < 32; ++kk)
            Wr[g][kk] = w_hh[j * 32 + kk];
    }

    float h = 0.0f, c = 0.0f;
    const float* xrow = x + (size_t)b * Tsz;
    float* orow = out + (size_t)b * (size_t)(Tsz * Hsz) + k;

    // Software-pipelined x tile: lane k holds x[b][t0+k]; broadcast per step.
    float xv = xrow[k];
    for (int t0 = 0; t0 < Tsz; t0 += 32) {
        float xv_next = (t0 + 32 < Tsz) ? xrow[t0 + 32 + k] : 0.0f;
#pragma unroll 4
        for (int tt = 0; tt < 32; ++tt) {
            float xt = __shfl(xv, tt, 32);
            float a0 = __fmaf_rn(wi[0], xt, bias[0]);
            float a1 = __fmaf_rn(wi[1], xt, bias[1]);
            float a2 = __fmaf_rn(wi[2], xt, bias[2]);
            float a3 = __fmaf_rn(wi[3], xt, bias[3]);
#pragma unroll
            for (int kk = 0; kk < 32; ++kk) {
                float hv = __shfl(h, kk, 32);
                a0 = __fmaf_rn(Wr[0][kk], hv, a0);
                a1 = __fmaf_rn(Wr[1][kk], hv, a1);
                a2 = __fmaf_rn(Wr[2][kk], hv, a2);
                a3 = __fmaf_rn(Wr[3][kk], hv, a3);
            }
            float ig = fast_sigmoid(a0);
            float fg = fast_sigmoid(a1);
            float gg = fast_tanh(a2);
            float og = fast_sigmoid(a3);
            c = __fmaf_rn(fg, c, ig * gg);
            h = og * fast_tanh(c);
            orow[(size_t)(t0 + tt) * Hsz] = h;
        }
        xv = xv_next;
    }
}

extern "C" void kernel_launch(void* const* d_in, const int* in_sizes, int n_in,
                              void* d_out, int out_size, void* d_ws, size_t ws_size,
                              hipStream_t stream) {
    const float* x    = (const float*)d_in[0];
    const float* w_ih = (const float*)d_in[1];
    const float* w_hh = (const float*)d_in[2];
    const float* b_ih = (const float*)d_in[3];
    const float* b_hh = (const float*)d_in[4];
    float* out = (float*)d_out;

    dim3 grid(Bsz / 8);   // 256 blocks = 1 per CU
    dim3 block(256);      // 8 batch rows x 32 hidden
    lstm_fwd_kernel<<<grid, block, 0, stream>>>(x, w_ih, w_hh, b_ih, b_hh, out);
}

// Round 2
// 606.884 us; speedup vs baseline: 1.9775x; 1.9775x over previous
//
#include <hip/hip_runtime.h>
#include <hip/hip_bf16.h>

// B=2048 rows, T=2048 steps, H=32. Thread = (b, k). Weights register-resident
// as packed float2 (v_pk_fma_f32 halves fp32 issue cost). h-broadcast via a
// per-row 128B LDS line: 1 ds_write_b32 + 8 ds_read_b128 per step, all
// wave-internal (rows never span waves) -> no barriers anywhere in the T loop.

#define Bsz 2048
#define Tsz 2048
#define Hsz 32

typedef float v2f __attribute__((ext_vector_type(2)));

__device__ __forceinline__ float fast_rcp(float x) {
    return __builtin_amdgcn_rcpf(x);
}
__device__ __forceinline__ float fast_sigmoid(float x) {
    float e = __builtin_amdgcn_exp2f(-1.44269504f * x);
    return fast_rcp(1.0f + e);
}
__device__ __forceinline__ float fast_tanh(float x) {
    float e = __builtin_amdgcn_exp2f(-2.88539008f * x);
    return __fmaf_rn(2.0f, fast_rcp(1.0f + e), -1.0f);
}

#if __has_builtin(__builtin_elementwise_fma)
__device__ __forceinline__ v2f pkfma(v2f a, v2f b, v2f c) {
    return __builtin_elementwise_fma(a, b, c);
}
#else
__device__ __forceinline__ v2f pkfma(v2f a, v2f b, v2f c) {
    v2f r; r.x = __fmaf_rn(a.x, b.x, c.x); r.y = __fmaf_rn(a.y, b.y, c.y); return r;
}
#endif

__global__ __launch_bounds__(256, 1) void lstm_fwd_kernel(
    const float* __restrict__ x,      // (B, T)
    const float* __restrict__ w_ih,   // (4H, 1)
    const float* __restrict__ w_hh,   // (4H, H)
    const float* __restrict__ b_ih,   // (4H,)
    const float* __restrict__ b_hh,   // (4H,)
    float* __restrict__ out)          // (B, T*H)
{
    __shared__ float hbuf[8][32];     // per-row h line (128B, float4-aligned)
    __shared__ float xbuf[8][32];     // per-row x tile

    const int k  = threadIdx.x & 31;
    const int lb = threadIdx.x >> 5;
    const int b  = blockIdx.x * 8 + lb;

    // ---- register-resident weights: rows k, 32+k, 64+k, 96+k of W_hh ----
    v2f W0[16], W1[16], W2[16], W3[16];
    float wi[4], bs[4];
#pragma unroll
    for (int g = 0; g < 4; ++g) {
        const int j = g * 32 + k;
        wi[g] = w_ih[j];
        bs[g] = b_ih[j] + b_hh[j];
    }
#define LOADW(G, ARR)                                                          \
    {                                                                          \
        const float4* wr =                                                     \
            reinterpret_cast<const float4*>(w_hh + (size_t)((G)*32 + k) * 32); \
        _Pragma("unroll") for (int q = 0; q < 8; ++q) {                        \
            float4 v = wr[q];                                                  \
            ARR[2 * q]     = (v2f){v.x, v.y};                                  \
            ARR[2 * q + 1] = (v2f){v.z, v.w};                                  \
        }                                                                      \
    }
    LOADW(0, W0) LOADW(1, W1) LOADW(2, W2) LOADW(3, W3)
#undef LOADW

    float h = 0.0f, c = 0.0f;
    hbuf[lb][k] = 0.0f;               // step-0 state (wave-internal ordering)

    const float* xrow = x + (size_t)b * Tsz;
    float* orow = out + (size_t)b * (size_t)(Tsz * Hsz) + k;
    const float4* hrow = reinterpret_cast<const float4*>(&hbuf[lb][0]);

    float xv = xrow[k];               // lane k holds x[b][t0+k]
    for (int t0 = 0; t0 < Tsz; t0 += 32) {
        xbuf[lb][k] = xv;
        float xv_next = (t0 + 32 < Tsz) ? xrow[t0 + 32 + k] : 0.0f;

#pragma unroll 4
        for (int tt = 0; tt < 32; ++tt) {
            // previous-step h of this row (written by our own wave's lanes)
            float4 h4[8];
#pragma unroll
            for (int q = 0; q < 8; ++q) h4[q] = hrow[q];

            float xt = xbuf[lb][tt];

            // 8 independent packed-FMA chains (2 per gate)
            v2f a0A = {0.f, 0.f}, a0B = {0.f, 0.f};
            v2f a1A = {0.f, 0.f}, a1B = {0.f, 0.f};
            v2f a2A = {0.f, 0.f}, a2B = {0.f, 0.f};
            v2f a3A = {0.f, 0.f}, a3B = {0.f, 0.f};
#pragma unroll
            for (int q = 0; q < 8; ++q) {
                v2f lo = (v2f){h4[q].x, h4[q].y};
                v2f hi = (v2f){h4[q].z, h4[q].w};
                if (q & 1) {
                    a0B = pkfma(W0[2 * q], lo, a0B); a0B = pkfma(W0[2 * q + 1], hi, a0B);
                    a1B = pkfma(W1[2 * q], lo, a1B); a1B = pkfma(W1[2 * q + 1], hi, a1B);
                    a2B = pkfma(W2[2 * q], lo, a2B); a2B = pkfma(W2[2 * q + 1], hi, a2B);
                    a3B = pkfma(W3[2 * q], lo, a3B); a3B = pkfma(W3[2 * q + 1], hi, a3B);
                } else {
                    a0A = pkfma(W0[2 * q], lo, a0A); a0A = pkfma(W0[2 * q + 1], hi, a0A);
                    a1A = pkfma(W1[2 * q], lo, a1A); a1A = pkfma(W1[2 * q + 1], hi, a1A);
                    a2A = pkfma(W2[2 * q], lo, a2A); a2A = pkfma(W2[2 * q + 1], hi, a2A);
                    a3A = pkfma(W3[2 * q], lo, a3A); a3A = pkfma(W3[2 * q + 1], hi, a3A);
                }
            }
            float p0 = (a0A.x + a0A.y) + (a0B.x + a0B.y) + __fmaf_rn(wi[0], xt, bs[0]);
            float p1 = (a1A.x + a1A.y) + (a1B.x + a1B.y) + __fmaf_rn(wi[1], xt, bs[1]);
            float p2 = (a2A.x + a2A.y) + (a2B.x + a2B.y) + __fmaf_rn(wi[2], xt, bs[2]);
            float p3 = (a3A.x + a3A.y) + (a3B.x + a3B.y) + __fmaf_rn(wi[3], xt, bs[3]);

            float ig = fast_sigmoid(p0);
            float fg = fast_sigmoid(p1);
            float gg = fast_tanh(p2);
            float og = fast_sigmoid(p3);
            c = __fmaf_rn(fg, c, ig * gg);
            h = og * fast_tanh(c);

            hbuf[lb][k] = h;                           // next step's input
            orow[(size_t)(t0 + tt) * Hsz] = h;         // coalesced 128B/row
        }
        xv = xv_next;
    }
}

extern "C" void kernel_launch(void* const* d_in, const int* in_sizes, int n_in,
                              void* d_out, int out_size, void* d_ws, size_t ws_size,
                              hipStream_t stream) {
    const float* x    = (const float*)d_in[0];
    const float* w_ih = (const float*)d_in[1];
    const float* w_hh = (const float*)d_in[2];
    const float* b_ih = (const float*)d_in[3];
    const float* b_hh = (const float*)d_in[4];
    float* out = (float*)d_out;

    dim3 grid(Bsz / 8);   // 256 blocks = 1 per CU
    dim3 block(256);      // 8 rows x 32 hidden; 4 waves/CU (structural max)
    lstm_fwd_kernel<<<grid, block, 0, stream>>>(x, w_ih, w_hh, b_ih, b_hh, out);
}